// Round 8
// baseline (875.879 us; speedup 1.0000x reference)
//
#include <hip/hip_runtime.h>

// OnlineDenoisingAutoencoder: LSTM(B=2048, T=2048, in=1, proj=16, H=32)
// R8: gate-split for TLP=2. 1 batch/wave (2048 waves = 2/SIMD). Lane =
// (half, j): half0 computes gates i,g of its j; half1 computes f,o. Cross-half
// exchange (2 reg swizzles) gives all 4 gate values to both halves; both
// redundantly compute c/h (cheap, keeps h duplicated for the gather).
// Dots: v_dot2_f32_f16, fp16 weights in regs (2 gates = 32 VGPRs), fp32 cell.
// h all-gather: R7's in-register net (ds_swizzle xor16 + v_perm + 15 DPP movs),
// lane-order self-discovered at setup by pushing (float)j through the net.
// Output proj: DPP reduce within half, lane 63 stores.
// History: R2 864us LDS-pipe-bound; R3 pk_fma not 2x (996); R4 readlane (1034);
// R6 fdot2+2batch/wave 670; R7 reg-gather 731 — both TLP=1 latency-exposed
// (~230 cyc/step stall, VALUBusy stuck ~70%). R8 restores TLP=2.

#define BB 2048
#define TT 2048
#define HH 32

typedef _Float16 h2 __attribute__((ext_vector_type(2)));

__device__ __forceinline__ float gate_eval(float x, float m, float a, float b) {
    // a * (1 / (1 + 2^(m*x))) + b ; sigmoid: m=-log2e,a=1,b=0 ; tanh: m=-2log2e,a=2,b=-1
    float e = __builtin_amdgcn_exp2f(x * m);
    float r = __builtin_amdgcn_rcpf(1.0f + e);
    return fmaf(a, r, b);
}

template <int CTRL>
__device__ __forceinline__ int dpp_mov(int v) {
    return __builtin_amdgcn_update_dpp(0, v, CTRL, 0xf, 0xf, true);
}

template <int CTRL>
__device__ __forceinline__ float dpp_add(float v) {
    int s = __builtin_amdgcn_update_dpp(0, __float_as_int(v), CTRL, 0xf, 0xf, true);
    return v + __int_as_float(s);
}

struct HVec { int v[16]; };   // 16 x packed fp16 pair

// All-gather one fp32 value per lane (within each 32-lane half) into 16 packed
// fp16 pairs. Ordering is arbitrary-but-fixed per lane; weights are loaded
// through the same network at setup, so any consistent permutation is correct.
__device__ __forceinline__ HVec gather_net(float h) {
    _Float16 hf = (_Float16)h;                                // RTN
    unsigned hb = (unsigned)__builtin_bit_cast(unsigned short, hf);
    int dup = (int)(hb | (hb << 16));                         // [h16|h16]
    int prt = __builtin_amdgcn_ds_swizzle(dup, 0x401F);       // lane ^ 16 (reg shuffle)
    HVec r;
    // bytes[0,1] = own h16, bytes[2,3] = partner h16
    r.v[0] = (int)__builtin_amdgcn_perm((unsigned)prt, (unsigned)dup, 0x07060100u);
    r.v[1] = dpp_mov<0xB1>(r.v[0]);                           // quad_perm xor1
    r.v[2] = dpp_mov<0x4E>(r.v[0]);                           // quad_perm xor2
    r.v[3] = dpp_mov<0x4E>(r.v[1]);
    r.v[4] = dpp_mov<0x124>(r.v[0]);                          // row_ror:4
    r.v[5] = dpp_mov<0x124>(r.v[1]);
    r.v[6] = dpp_mov<0x124>(r.v[2]);
    r.v[7] = dpp_mov<0x124>(r.v[3]);
    r.v[8]  = dpp_mov<0x128>(r.v[0]);                         // row_ror:8
    r.v[9]  = dpp_mov<0x128>(r.v[1]);
    r.v[10] = dpp_mov<0x128>(r.v[2]);
    r.v[11] = dpp_mov<0x128>(r.v[3]);
    r.v[12] = dpp_mov<0x128>(r.v[4]);
    r.v[13] = dpp_mov<0x128>(r.v[5]);
    r.v[14] = dpp_mov<0x128>(r.v[6]);
    r.v[15] = dpp_mov<0x128>(r.v[7]);
    return r;
}

__global__ __launch_bounds__(256) void lstm_fused_kernel(
    const float* __restrict__ x_seq,  // [B,T,1]
    const float* __restrict__ Wp,     // [16,1]
    const float* __restrict__ bp,     // [16]
    const float* __restrict__ W_ih,   // [128,16]
    const float* __restrict__ W_hh,   // [128,32]
    const float* __restrict__ b_ih,   // [128]
    const float* __restrict__ b_hh,   // [128]
    const float* __restrict__ Wo,     // [1,32]
    const float* __restrict__ bo,     // [1]
    float* __restrict__ out)          // [B,T,1] fp32
{
    const int tid  = threadIdx.x;
    const int wave = tid >> 6;
    const int lane = tid & 63;
    const int half = lane >> 5;      // 0: gates i,g ; 1: gates f,o
    const int j    = lane & 31;      // hidden index this lane owns
    const int b    = blockIdx.x * 4 + wave;   // 1 batch per wave

    // PyTorch gate rows: i=[0,32), f=[32,64), g=[64,96), o=[96,128)
    const int r1 = half * HH + j;          // i_j (half0) or f_j (half1)
    const int r2 = 2 * HH + half * HH + j; // g_j (half0) or o_j (half1)

    // ---- discover this lane's gather ordering, load W_hh in that order ----
    HVec idx = gather_net((float)j);   // fp16 holds small ints exactly
    h2 w1[16], w2[16];
    {
        const float* p1 = W_hh + r1 * HH;
        const float* p2 = W_hh + r2 * HH;
#pragma unroll
        for (int s = 0; s < 16; ++s) {
            h2 iv = __builtin_bit_cast(h2, idx.v[s]);
            int kx = (int)(float)iv.x;
            int ky = (int)(float)iv.y;
            w1[s].x = (_Float16)p1[kx]; w1[s].y = (_Float16)p1[ky];
            w2[s].x = (_Float16)p2[kx]; w2[s].y = (_Float16)p2[ky];
        }
    }

    // ---- collapse input pipeline: pre-act = dot + x*a + c (INPUT_DIM==1) ----
    float a1 = 0.f, c1 = 0.f, a2 = 0.f, c2 = 0.f;
#pragma unroll
    for (int p = 0; p < 16; ++p) {
        float wpv = Wp[p], bpv = bp[p];
        float wi1 = W_ih[r1 * 16 + p], wi2 = W_ih[r2 * 16 + p];
        a1 = fmaf(wi1, wpv, a1);  c1 = fmaf(wi1, bpv, c1);
        a2 = fmaf(wi2, wpv, a2);  c2 = fmaf(wi2, bpv, c2);
    }
    c1 += b_ih[r1] + b_hh[r1];
    c2 += b_ih[r2] + b_hh[r2];

    const float LOG2E = 1.44269504088896340736f;
    // gate1 (i or f): sigmoid. gate2: tanh(g) on half0, sigmoid(o) on half1.
    const float m2  = half ? -LOG2E : -2.0f * LOG2E;
    const float a2c = half ? 1.0f : 2.0f;
    const float b2c = half ? 0.0f : -1.0f;

    const float woj = Wo[j];
    const float bo0 = bo[0];

    float c = 0.0f;
    const float* xp = x_seq + (size_t)b * TT;
    float* op = out + (size_t)b * TT;

    HVec hcur;
#pragma unroll
    for (int s = 0; s < 16; ++s) hcur.v[s] = 0;   // h0 = 0

    float4 x4 = *(const float4*)(xp);

    for (int t = 0; t < TT; t += 4) {
        const int tn = (t + 4 < TT) ? (t + 4) : t;
        float4 x4n = *(const float4*)(xp + tn);   // prefetch next group
        float outv[4];
#pragma unroll
        for (int u = 0; u < 4; ++u) {
            float xv = (u == 0) ? x4.x : (u == 1) ? x4.y : (u == 2) ? x4.z : x4.w;

            // 2 gate dots over h (fp16 inputs, fp32 accum), 2 accumulators each
            float s10 = c1, s11 = xv * a1;
            float s20 = c2, s21 = xv * a2;
#pragma unroll
            for (int k = 0; k < 16; k += 2) {
                h2 h0 = __builtin_bit_cast(h2, hcur.v[k]);
                h2 h1 = __builtin_bit_cast(h2, hcur.v[k + 1]);
                s10 = __builtin_amdgcn_fdot2(w1[k],     h0, s10, false);
                s20 = __builtin_amdgcn_fdot2(w2[k],     h0, s20, false);
                s11 = __builtin_amdgcn_fdot2(w1[k + 1], h1, s11, false);
                s21 = __builtin_amdgcn_fdot2(w2[k + 1], h1, s21, false);
            }

            float v1 = gate_eval(s10 + s11, -LOG2E, 1.0f, 0.0f); // sigmoid(i|f)
            float v2 = gate_eval(s20 + s21, m2, a2c, b2c);       // tanh(g)|sigm(o)

            // exchange across halves (register swizzle, no LDS memory)
            float p1v = __shfl_xor(v1, 32, 64);
            float p2v = __shfl_xor(v2, 32, 64);
            float iv = half ? p1v : v1;
            float fv = half ? v1 : p1v;
            float gv = half ? p2v : v2;
            float ov = half ? v2 : p2v;

            c = fmaf(fv, c, iv * gv);
            float th = gate_eval(c, -2.0f * LOG2E, 2.0f, -1.0f); // tanh(c)
            float h = ov * th;

            // in-register all-gather of h for the next step
            hcur = gather_net(h);

            // fused output projection: width-32 DPP reduce (h duplicated/half)
            float po = woj * h;
            po = dpp_add<0x111>(po);
            po = dpp_add<0x112>(po);
            po = dpp_add<0x114>(po);
            po = dpp_add<0x118>(po);
            po = dpp_add<0x142>(po);   // row_bcast15 -> lane 31/63 hold the sum
            outv[u] = po + bo0;
        }
        if (lane == 63) {
            *(float4*)(op + t) = make_float4(outv[0], outv[1], outv[2], outv[3]);
        }
        x4 = x4n;
    }
}

extern "C" void kernel_launch(void* const* d_in, const int* in_sizes, int n_in,
                              void* d_out, int out_size, void* d_ws, size_t ws_size,
                              hipStream_t stream) {
    const float* x_seq = (const float*)d_in[0];
    const float* Wp    = (const float*)d_in[1];
    const float* bp    = (const float*)d_in[2];
    const float* W_ih  = (const float*)d_in[3];
    const float* W_hh  = (const float*)d_in[4];
    const float* b_ih  = (const float*)d_in[5];
    const float* b_hh  = (const float*)d_in[6];
    const float* Wo    = (const float*)d_in[7];
    const float* bo    = (const float*)d_in[8];
    float* out = (float*)d_out;

    dim3 grid(BB / 4);   // 4 waves/block, 1 batch/wave -> 2048 waves (TLP=2)
    dim3 block(256);
    lstm_fused_kernel<<<grid, block, 0, stream>>>(
        x_seq, Wp, bp, W_ih, W_hh, b_ih, b_hh, Wo, bo, out);
}

// Round 9
// 716.621 us; speedup vs baseline: 1.2222x; 1.2222x over previous
//
#include <hip/hip_runtime.h>

// OnlineDenoisingAutoencoder: LSTM(B=2048, T=2048, in=1, proj=16, H=32)
// R9 = R6 (champion, 670us) + f16 transcendentals + scale-folding.
// Issue model (calibrated on R2/R6/R8 busy counters): v_fma 2cyc,
// v_dot2_f32_f16 4cyc, f32 trans ~16cyc, f16 trans ~2cyc. R6 budget/wave-step:
// dots 256 + trans 160 + misc 110. This round cuts trans 160 -> ~50 by
// evaluating sigmoid/tanh cores in f16 (v_exp_f16 + v_add_f16 + v_rcp_f16),
// with the -log2e / -2log2e input scales pre-folded into W_hh/W_ih/biases.
// Cell state c stays fp32; gate eval err ~5e-4 (same scale as fp16-h rounding).
// Layout (R6): 2 batches/wave (half=batch, j=lane&31), all 4 gates per lane,
// fdot2 f32-accum dots, fp16 h via per-wave LDS (write + 4x ds_read_b128),
// DPP output reduce, lane 31/63 store. 1024 waves.
// History: R2 864 (fp32, LDS); R3 pk_fma_f32 not 2x (996); R4 readlane (1034);
// R6 670; R7 reg-gather +9% (731); R8 gate-split TLP=2 redundancy (875).

#define BB 2048
#define TT 2048
#define HH 32

typedef _Float16 h2 __attribute__((ext_vector_type(2)));

// sigmoid from pre-scaled input: s = -log2e * x  ->  1/(1+2^s), f16 core.
__device__ __forceinline__ float sig_from_scaled(float s) {
    unsigned short p = __builtin_bit_cast(unsigned short, (_Float16)s);
    unsigned short e, t, r;
    asm("v_exp_f16 %0, %1" : "=v"(e) : "v"(p));
    asm("v_add_f16 %0, 1.0, %1" : "=v"(t) : "v"(e));  // inline 1.0 in src0
    asm("v_rcp_f16 %0, %1" : "=v"(r) : "v"(t));
    return (float)__builtin_bit_cast(_Float16, r);
}
// tanh from pre-scaled input: s = -2*log2e * z -> 2/(1+2^s) - 1
__device__ __forceinline__ float tanh_from_scaled(float s) {
    return fmaf(2.0f, sig_from_scaled(s), -1.0f);
}

template <int CTRL>
__device__ __forceinline__ float dpp_add(float v) {
    int s = __builtin_amdgcn_update_dpp(0, __float_as_int(v), CTRL, 0xf, 0xf, true);
    return v + __int_as_float(s);
}

struct HVec { h2 v[16]; };

__device__ __forceinline__ HVec gather_h(const _Float16* base) {
    const float4* p = (const float4*)base;   // 64 B = 4 x ds_read_b128 (broadcast)
    float4 q0 = p[0], q1 = p[1], q2 = p[2], q3 = p[3];
    HVec r;
    r.v[0]  = __builtin_bit_cast(h2, q0.x); r.v[1]  = __builtin_bit_cast(h2, q0.y);
    r.v[2]  = __builtin_bit_cast(h2, q0.z); r.v[3]  = __builtin_bit_cast(h2, q0.w);
    r.v[4]  = __builtin_bit_cast(h2, q1.x); r.v[5]  = __builtin_bit_cast(h2, q1.y);
    r.v[6]  = __builtin_bit_cast(h2, q1.z); r.v[7]  = __builtin_bit_cast(h2, q1.w);
    r.v[8]  = __builtin_bit_cast(h2, q2.x); r.v[9]  = __builtin_bit_cast(h2, q2.y);
    r.v[10] = __builtin_bit_cast(h2, q2.z); r.v[11] = __builtin_bit_cast(h2, q2.w);
    r.v[12] = __builtin_bit_cast(h2, q3.x); r.v[13] = __builtin_bit_cast(h2, q3.y);
    r.v[14] = __builtin_bit_cast(h2, q3.z); r.v[15] = __builtin_bit_cast(h2, q3.w);
    return r;
}

__global__ __launch_bounds__(256) void lstm_fused_kernel(
    const float* __restrict__ x_seq,  // [B,T,1]
    const float* __restrict__ Wp,     // [16,1]
    const float* __restrict__ bp,     // [16]
    const float* __restrict__ W_ih,   // [128,16]
    const float* __restrict__ W_hh,   // [128,32]
    const float* __restrict__ b_ih,   // [128]
    const float* __restrict__ b_hh,   // [128]
    const float* __restrict__ Wo,     // [1,32]
    const float* __restrict__ bo,     // [1]
    float* __restrict__ out)          // [B,T,1] fp32
{
    const int tid  = threadIdx.x;
    const int wave = tid >> 6;
    const int lane = tid & 63;
    const int half = lane >> 5;      // which of the wave's 2 batch elements
    const int j    = lane & 31;      // hidden index this lane owns
    const int b    = blockIdx.x * 8 + wave * 2 + half;

    // PyTorch gate row order: i=[0,32), f=[32,64), g=[64,96), o=[96,128)
    const int rI = j, rF = HH + j, rG = 2 * HH + j, rO = 3 * HH + j;

    const float MS = -1.44269504088896340736f;   // -log2e   (sigmoid scale)
    const float MT = -2.88539008177792681472f;   // -2*log2e (tanh scale)

    // ---- W_hh rows (4 gates) into registers, PRE-SCALED, packed fp16 pairs ----
    h2 wI[16], wF[16], wG[16], wO[16];
    {
        const float2* pI = (const float2*)(W_hh + rI * HH);
        const float2* pF = (const float2*)(W_hh + rF * HH);
        const float2* pG = (const float2*)(W_hh + rG * HH);
        const float2* pO = (const float2*)(W_hh + rO * HH);
#pragma unroll
        for (int k = 0; k < 16; ++k) {
            float2 a = pI[k], f = pF[k], g = pG[k], o = pO[k];
            wI[k].x = (_Float16)(MS * a.x); wI[k].y = (_Float16)(MS * a.y);
            wF[k].x = (_Float16)(MS * f.x); wF[k].y = (_Float16)(MS * f.y);
            wG[k].x = (_Float16)(MT * g.x); wG[k].y = (_Float16)(MT * g.y);
            wO[k].x = (_Float16)(MS * o.x); wO[k].y = (_Float16)(MS * o.y);
        }
    }

    // ---- collapse input pipeline: pre-act = dot + x*a + c (INPUT_DIM==1) ----
    float aI = 0.f, cI = 0.f, aF = 0.f, cF = 0.f;
    float aG = 0.f, cG = 0.f, aO = 0.f, cO = 0.f;
#pragma unroll
    for (int p = 0; p < 16; ++p) {
        float wpv = Wp[p], bpv = bp[p];
        float wi = W_ih[rI * 16 + p], wf = W_ih[rF * 16 + p];
        float wg = W_ih[rG * 16 + p], wo_ = W_ih[rO * 16 + p];
        aI = fmaf(wi, wpv, aI);  cI = fmaf(wi, bpv, cI);
        aF = fmaf(wf, wpv, aF);  cF = fmaf(wf, bpv, cF);
        aG = fmaf(wg, wpv, aG);  cG = fmaf(wg, bpv, cG);
        aO = fmaf(wo_, wpv, aO); cO = fmaf(wo_, bpv, cO);
    }
    cI += b_ih[rI] + b_hh[rI];
    cF += b_ih[rF] + b_hh[rF];
    cG += b_ih[rG] + b_hh[rG];
    cO += b_ih[rO] + b_hh[rO];
    // fold the eval scales into the x-path coefficients too
    aI *= MS; cI *= MS;  aF *= MS; cF *= MS;
    aG *= MT; cG *= MT;  aO *= MS; cO *= MS;

    const float woj = Wo[j];
    const float bo0 = bo[0];

    // per-(wave,batch) h buffer, fp16, 64 B each
    __shared__ __align__(16) _Float16 hsh[4][2][HH];
    _Float16* hbase = &hsh[wave][half][0];
    hbase[j] = (_Float16)0.0f;

    float c = 0.0f;
    const float* xp = x_seq + (size_t)b * TT;
    float* op = out + (size_t)b * TT;

    HVec hcur = gather_h(hbase);            // zeros (same-wave DS order)
    float4 x4 = *(const float4*)(xp);

    for (int t = 0; t < TT; t += 4) {
        const int tn = (t + 4 < TT) ? (t + 4) : t;
        float4 x4n = *(const float4*)(xp + tn);   // prefetch next group
        float outv[4];
#pragma unroll
        for (int u = 0; u < 4; ++u) {
            float xv = (u == 0) ? x4.x : (u == 1) ? x4.y : (u == 2) ? x4.z : x4.w;

            // 4 gate dots over h (fp16 inputs, fp32 accum), 2 accumulators each;
            // even chain starts from inline 0, odd chain carries x-term + bias.
            float sI0 = 0.f, sI1 = fmaf(xv, aI, cI);
            float sF0 = 0.f, sF1 = fmaf(xv, aF, cF);
            float sG0 = 0.f, sG1 = fmaf(xv, aG, cG);
            float sO0 = 0.f, sO1 = fmaf(xv, aO, cO);
#pragma unroll
            for (int k = 0; k < 16; k += 2) {
                h2 h0 = hcur.v[k], h1 = hcur.v[k + 1];
                sI0 = __builtin_amdgcn_fdot2(wI[k],     h0, sI0, false);
                sF0 = __builtin_amdgcn_fdot2(wF[k],     h0, sF0, false);
                sG0 = __builtin_amdgcn_fdot2(wG[k],     h0, sG0, false);
                sO0 = __builtin_amdgcn_fdot2(wO[k],     h0, sO0, false);
                sI1 = __builtin_amdgcn_fdot2(wI[k + 1], h1, sI1, false);
                sF1 = __builtin_amdgcn_fdot2(wF[k + 1], h1, sF1, false);
                sG1 = __builtin_amdgcn_fdot2(wG[k + 1], h1, sG1, false);
                sO1 = __builtin_amdgcn_fdot2(wO[k + 1], h1, sO1, false);
            }

            float iv = sig_from_scaled(sI0 + sI1);
            float fv = sig_from_scaled(sF0 + sF1);
            float gv = tanh_from_scaled(sG0 + sG1);
            float ov = sig_from_scaled(sO0 + sO1);

            c = fmaf(fv, c, iv * gv);
            float th = tanh_from_scaled(c * MT);
            float h = ov * th;

            // publish h, then issue next gather; DPP reduce below overlaps latency
            hbase[j] = (_Float16)h;
            hcur = gather_h(hbase);

            // fused output projection: width-32 reduce on VALU via DPP.
            float po = woj * h;
            po = dpp_add<0x111>(po);
            po = dpp_add<0x112>(po);
            po = dpp_add<0x114>(po);
            po = dpp_add<0x118>(po);
            po = dpp_add<0x142>(po);   // row_bcast15 -> lane 31/63 hold the sum
            outv[u] = po + bo0;
        }
        if ((lane & 31) == 31) {
            *(float4*)(op + t) = make_float4(outv[0], outv[1], outv[2], outv[3]);
        }
        x4 = x4n;
    }
}

extern "C" void kernel_launch(void* const* d_in, const int* in_sizes, int n_in,
                              void* d_out, int out_size, void* d_ws, size_t ws_size,
                              hipStream_t stream) {
    const float* x_seq = (const float*)d_in[0];
    const float* Wp    = (const float*)d_in[1];
    const float* bp    = (const float*)d_in[2];
    const float* W_ih  = (const float*)d_in[3];
    const float* W_hh  = (const float*)d_in[4];
    const float* b_ih  = (const float*)d_in[5];
    const float* b_hh  = (const float*)d_in[6];
    const float* Wo    = (const float*)d_in[7];
    const float* bo    = (const float*)d_in[8];
    float* out = (float*)d_out;

    dim3 grid(BB / 8);   // 4 waves/block, 2 batch elements/wave
    dim3 block(256);
    lstm_fused_kernel<<<grid, block, 0, stream>>>(
        x_seq, Wp, bp, W_ih, W_hh, b_ih, b_hh, Wo, bo, out);
}